// Round 25
// baseline (149.976 us; speedup 1.0000x reference)
//
#include <hip/hip_runtime.h>
#include <stdint.h>

#define BN_EPS 1e-3f

constexpr int Bn = 32, H = 56, Wd = 56, C = 256;
constexpr int NSLOT = 232;          // 4 staged input rows * 58 cols (w/ halo)
typedef int v4i __attribute__((ext_vector_type(4)));

__device__ __forceinline__ int imax(int a, int b) { return a > b ? a : b; }

__device__ __forceinline__ uint32_t pack4(float4 f) {
  return (f.x >= 0.f ? 0x01u : 0xFFu) | ((f.y >= 0.f ? 0x01u : 0xFFu) << 8) |
         ((f.z >= 0.f ? 0x01u : 0xFFu) << 16) |
         ((f.w >= 0.f ? 0x01u : 0xFFu) << 24);
}

// ---------------------------------------------------------------------------
// Fragment-contiguous weights (verified R12 layout), BOTH tensors in one
// launch: u0 < 147456 -> w1, else w2.
// wT2 bytes [f = (tap*4+icq)*16 + ocg][l = grp*16+lid][bb 0..15]
//   = sign(w[tap][ic = icq*64 + grp*16 + bb][oc = ocg*16 + lid])
__global__ __launch_bounds__(256) void k_sign_wT2(
    const float* __restrict__ w1s, const float* __restrict__ w2s,
    uint32_t* __restrict__ wt1, uint32_t* __restrict__ wt2) {
  int u0 = blockIdx.x * 256 + threadIdx.x;  // 0..294911
  const int half = (u0 >= 147456) ? 1 : 0;
  const float* w = half ? w2s : w1s;
  uint32_t* wt = half ? wt2 : wt1;
  int u = u0 - half * 147456;
  int f = u >> 8, r = u & 255;
  int l = r >> 2, w4 = r & 3;
  int grp = l >> 4, lid = l & 15;
  int tap = f >> 6, icq = (f >> 4) & 3, ocg = f & 15;
  int oc = ocg * 16 + lid;
  uint32_t pk = 0;
#pragma unroll
  for (int j = 0; j < 4; ++j) {
    int ic = icq * 64 + grp * 16 + w4 * 4 + j;
    float v = w[((size_t)(tap * 256 + ic)) * 256 + oc];
    pk |= (v >= 0.f ? 0x01u : 0xFFu) << (8 * j);
  }
  wt[u] = pk;
}

// ---------------------------------------------------------------------------
// Per-wave GEMM body (R16/R22/R24 verbatim). Wave = 7 msub x 2 nsub (N=32
// slice): zero B redundancy, acc[7][2] = 56 VGPR, 4 waves/SIMD.
// m permuted (row=m&1, col=m>>1) -> 2x2 pool = lane-local q-quad.
// A in LDS, XOR-swizzled: byte(slot s, off o) = s*256 + (o ^ ((s&7)<<4)).
// Epilogue stores are NON-TEMPORAL: hs is only read by the NEXT kernel, out
// is never re-read -> keep them from evicting the L2 working set (hs halo).
template <int MODE>
__device__ __forceinline__ void conv_body(
    const int8_t* As, const int8_t* __restrict__ wT2, int wn, int lane,
    const float* __restrict__ beta, const float* __restrict__ mean,
    const float* __restrict__ var, int8_t* __restrict__ hs,
    float* __restrict__ outp, int b, int rp)
{
  const int grp = lane >> 4, lid = lane & 15;
  const int wbase = wn * 32;
  const int cstg = grp << 4;

  int sb[7];
#pragma unroll
  for (int ms = 0; ms < 7; ++ms) {
    const int m = ms * 16 + lid;
    sb[ms] = (m & 1) * 58 + (m >> 1);
  }

  // wave's B slice: ocg in {2wn, 2wn+1} -> contiguous 2KB per step
  const int8_t* bpl = wT2 + (size_t)wn * 2048 + (size_t)lane * 16;

  v4i acc[7][2];
#pragma unroll
  for (int i = 0; i < 7; ++i)
#pragma unroll
    for (int j = 0; j < 2; ++j) acc[i][j] = (v4i){0, 0, 0, 0};

#define LOADB(dst, st)                                                     \
  {                                                                        \
    const int8_t* p_ = bpl + (size_t)(st) * 16384;                         \
    dst[0] = *(const v4i*)(p_);                                            \
    dst[1] = *(const v4i*)(p_ + 1024);                                     \
  }

#define LOADA(dst, st)                                                     \
  {                                                                        \
    const int tap_ = (st) >> 2, icq_ = (st) & 3;                           \
    const int ky_ = (tap_ >= 6) ? 2 : ((tap_ >= 3) ? 1 : 0);               \
    const int kx_ = tap_ - 3 * ky_;                                        \
    const int D_ = ky_ * 58 + kx_;                                         \
    const int ko_ = cstg + icq_ * 64;                                      \
    _Pragma("unroll") for (int ms = 0; ms < 7; ++ms) {                     \
      const int s_ = sb[ms] + D_;                                          \
      dst[ms] = *(const v4i*)(As + (s_ << 8) + (ko_ ^ ((s_ & 7) << 4)));   \
    }                                                                      \
  }

#define MFMAC(af, bf)                                                      \
  __builtin_amdgcn_s_setprio(1);                                           \
  _Pragma("unroll") for (int ms = 0; ms < 7; ++ms)                         \
  _Pragma("unroll") for (int ns = 0; ns < 2; ++ns)                         \
      acc[ms][ns] = __builtin_amdgcn_mfma_i32_16x16x64_i8(                 \
          af[ms], bf[ns], acc[ms][ns], 0, 0, 0);                           \
  __builtin_amdgcn_s_setprio(0);

  v4i af[7], bfA[2], bfB[2];
  LOADB(bfA, 0)

#pragma unroll 1
  for (int i = 0; i < 18; ++i) {
    const int s0 = 2 * i, s1 = 2 * i + 1;
    const int s2 = (s1 + 1 > 35) ? 35 : s1 + 1;
    LOADB(bfB, s1)            // prefetch next step's B under this MFMA cluster
    LOADA(af, s0)
    MFMAC(af, bfA)
    LOADB(bfA, s2)
    LOADA(af, s1)
    MFMAC(af, bfB)
  }

#undef MFMAC
#undef LOADA
#undef LOADB

  const int rA = rp * 2;
  if (MODE == 0) {
    // BN1 + sign -> hs (standard NHWC i8), non-temporal
#pragma unroll
    for (int ns = 0; ns < 2; ++ns) {
      const int oc = wbase + ns * 16 + lid;
      const float mu = mean[oc], rs = rsqrtf(var[oc] + BN_EPS), be = beta[oc];
#pragma unroll
      for (int ms = 0; ms < 7; ++ms)
#pragma unroll
        for (int q = 0; q < 4; ++q) {
          const int m = ms * 16 + grp * 4 + q;
          const int lr = m & 1, col = m >> 1;
          const float bnv = ((float)acc[ms][ns][q] - mu) * rs + be;
          __builtin_nontemporal_store(
              bnv >= 0.f ? (int8_t)1 : (int8_t)-1,
              &hs[(((size_t)(b * 56 + rA + lr)) * 56 + col) * 256 + oc]);
        }
    }
  } else {
    // maxpool (lane-local q-quad) + BN2 -> f32, non-temporal
#pragma unroll
    for (int ns = 0; ns < 2; ++ns) {
      const int oc = wbase + ns * 16 + lid;
      const float mu = mean[oc], rs = rsqrtf(var[oc] + BN_EPS), be = beta[oc];
#pragma unroll
      for (int ms = 0; ms < 7; ++ms) {
        const int mx = imax(imax(acc[ms][ns][0], acc[ms][ns][1]),
                            imax(acc[ms][ns][2], acc[ms][ns][3]));
        const int j = ms * 4 + grp;   // pooled col 0..27
        __builtin_nontemporal_store(
            ((float)mx - mu) * rs + be,
            &outp[(((size_t)(b * 28 + rp)) * 28 + j) * 256 + oc]);
      }
    }
  }
}

// ---------------------------------------------------------------------------
// 8 waves, each = N=32 slice x all of M=112 (R16 shape). MODE 0 fuses
// sign(x) (R22 staging). 1D grid of 896 blocks with BIJECTIVE XCD SWIZZLE
// (R24): XCD k owns images 4k..4k+3 completely -> halo re-reads and
// conv1->conv2 hs traffic stay in the XCD's 4MB L2.
template <int MODE>
__global__ __launch_bounds__(512, 4) void k_conv(
    const void* __restrict__ srcv, const int8_t* __restrict__ wT2,
    const float* __restrict__ beta, const float* __restrict__ mean,
    const float* __restrict__ var,
    int8_t* __restrict__ hs, float* __restrict__ outp)
{
  const int t = threadIdx.x;
  const int v = blockIdx.x;                 // 0..895
  const int swz = (v & 7) * 112 + (v >> 3); // XCD k -> contiguous 112 blocks
  const int b = swz / 28;                   // image 0..31
  const int rp = swz - b * 28;              // row pair 0..27
  const int rr0 = rp * 2;

  __shared__ __align__(16) int8_t As[NSLOT * 256];   // 59392 B

  // Stage A once (verified R22 pattern; MODE 0 packs f32 -> i8 signs).
  for (int i = t; i < NSLOT * 16; i += 512) {
    const int s = i >> 4, c = i & 15;
    const int lr = s / 58, colst = s - lr * 58;
    const int sr = rr0 + lr - 1, sc = colst - 1;
    uint4 vv;
    vv.x = vv.y = vv.z = vv.w = 0u;
    if ((unsigned)sr < 56u && (unsigned)sc < 56u) {
      if (MODE == 0) {
        const float* p = (const float*)srcv +
                         ((((size_t)(b * 56 + sr)) * 56 + sc) * 256 + c * 16);
        const float4* p4 = (const float4*)p;
        vv.x = pack4(p4[0]); vv.y = pack4(p4[1]);
        vv.z = pack4(p4[2]); vv.w = pack4(p4[3]);
      } else {
        vv = *(const uint4*)((const int8_t*)srcv +
                             (((size_t)(b * 56 + sr)) * 56 + sc) * 256 + c * 16);
      }
    }
    *(uint4*)(As + (s << 8) + ((c << 4) ^ ((s & 7) << 4))) = vv;
  }
  __syncthreads();

  const int lane = t & 63;
  const int wn = t >> 6;              // 0..7
  conv_body<MODE>(As, wT2, wn, lane, beta, mean, var, hs, outp, b, rp);
}

// ---------------------------------------------------------------------------
extern "C" void kernel_launch(void* const* d_in, const int* in_sizes, int n_in,
                              void* d_out, int out_size, void* d_ws, size_t ws_size,
                              hipStream_t stream) {
  const float* x     = (const float*)d_in[0];
  const float* w1    = (const float*)d_in[1];
  const float* beta1 = (const float*)d_in[2];
  const float* mean1 = (const float*)d_in[3];
  const float* var1  = (const float*)d_in[4];
  const float* w2    = (const float*)d_in[5];
  const float* beta2 = (const float*)d_in[6];
  const float* mean2 = (const float*)d_in[7];
  const float* var2  = (const float*)d_in[8];
  float* out = (float*)d_out;

  const size_t NPIX = (size_t)Bn * H * Wd * C;  // 25690112
  int8_t* hs  = (int8_t*)d_ws;
  int8_t* w1t = hs + NPIX;
  int8_t* w2t = w1t + 589824;

  k_sign_wT2<<<dim3(1152), 256, 0, stream>>>(w1, w2, (uint32_t*)w1t,
                                             (uint32_t*)w2t);
  k_conv<0><<<dim3(896), 512, 0, stream>>>(x, w1t, beta1, mean1, var1, hs, nullptr);
  k_conv<1><<<dim3(896), 512, 0, stream>>>(hs, w2t, beta2, mean2, var2, nullptr, out);
}

// Round 26
// 128.634 us; speedup vs baseline: 1.1659x; 1.1659x over previous
//
#include <hip/hip_runtime.h>
#include <stdint.h>

#define BN_EPS 1e-3f

constexpr int Bn = 32, H = 56, Wd = 56, C = 256;
constexpr int NSLOT = 232;          // 4 staged input rows * 58 cols (w/ halo)
typedef int v4i __attribute__((ext_vector_type(4)));

__device__ __forceinline__ int imax(int a, int b) { return a > b ? a : b; }

__device__ __forceinline__ uint32_t pack4(float4 f) {
  return (f.x >= 0.f ? 0x01u : 0xFFu) | ((f.y >= 0.f ? 0x01u : 0xFFu) << 8) |
         ((f.z >= 0.f ? 0x01u : 0xFFu) << 16) |
         ((f.w >= 0.f ? 0x01u : 0xFFu) << 24);
}

// ---------------------------------------------------------------------------
// Fragment-contiguous weights (verified R12 layout), BOTH tensors in one
// launch: u0 < 147456 -> w1, else w2.
// wT2 bytes [f = (tap*4+icq)*16 + ocg][l = grp*16+lid][bb 0..15]
//   = sign(w[tap][ic = icq*64 + grp*16 + bb][oc = ocg*16 + lid])
__global__ __launch_bounds__(256) void k_sign_wT2(
    const float* __restrict__ w1s, const float* __restrict__ w2s,
    uint32_t* __restrict__ wt1, uint32_t* __restrict__ wt2) {
  int u0 = blockIdx.x * 256 + threadIdx.x;  // 0..294911
  const int half = (u0 >= 147456) ? 1 : 0;
  const float* w = half ? w2s : w1s;
  uint32_t* wt = half ? wt2 : wt1;
  int u = u0 - half * 147456;
  int f = u >> 8, r = u & 255;
  int l = r >> 2, w4 = r & 3;
  int grp = l >> 4, lid = l & 15;
  int tap = f >> 6, icq = (f >> 4) & 3, ocg = f & 15;
  int oc = ocg * 16 + lid;
  uint32_t pk = 0;
#pragma unroll
  for (int j = 0; j < 4; ++j) {
    int ic = icq * 64 + grp * 16 + w4 * 4 + j;
    float v = w[((size_t)(tap * 256 + ic)) * 256 + oc];
    pk |= (v >= 0.f ? 0x01u : 0xFFu) << (8 * j);
  }
  wt[u] = pk;
}

// ---------------------------------------------------------------------------
// Per-wave GEMM body (R16/R22/R24 verbatim — best measured). Wave = 7 msub
// x 2 nsub (N=32 slice): zero B redundancy, acc[7][2] = 56 VGPR, 4 w/SIMD.
// m permuted (row=m&1, col=m>>1) -> 2x2 pool = lane-local q-quad.
// A in LDS, XOR-swizzled: byte(slot s, off o) = s*256 + (o ^ ((s&7)<<4)).
// Plain (cached) epilogue stores — NT stores regressed 5x on WRITE_SIZE
// (R25: byte-granular NT defeats L2 write-combining).
template <int MODE>
__device__ __forceinline__ void conv_body(
    const int8_t* As, const int8_t* __restrict__ wT2, int wn, int lane,
    const float* __restrict__ beta, const float* __restrict__ mean,
    const float* __restrict__ var, int8_t* __restrict__ hs,
    float* __restrict__ outp, int b, int rp)
{
  const int grp = lane >> 4, lid = lane & 15;
  const int wbase = wn * 32;
  const int cstg = grp << 4;

  int sb[7];
#pragma unroll
  for (int ms = 0; ms < 7; ++ms) {
    const int m = ms * 16 + lid;
    sb[ms] = (m & 1) * 58 + (m >> 1);
  }

  // wave's B slice: ocg in {2wn, 2wn+1} -> contiguous 2KB per step
  const int8_t* bpl = wT2 + (size_t)wn * 2048 + (size_t)lane * 16;

  v4i acc[7][2];
#pragma unroll
  for (int i = 0; i < 7; ++i)
#pragma unroll
    for (int j = 0; j < 2; ++j) acc[i][j] = (v4i){0, 0, 0, 0};

#define LOADB(dst, st)                                                     \
  {                                                                        \
    const int8_t* p_ = bpl + (size_t)(st) * 16384;                         \
    dst[0] = *(const v4i*)(p_);                                            \
    dst[1] = *(const v4i*)(p_ + 1024);                                     \
  }

#define LOADA(dst, st)                                                     \
  {                                                                        \
    const int tap_ = (st) >> 2, icq_ = (st) & 3;                           \
    const int ky_ = (tap_ >= 6) ? 2 : ((tap_ >= 3) ? 1 : 0);               \
    const int kx_ = tap_ - 3 * ky_;                                        \
    const int D_ = ky_ * 58 + kx_;                                         \
    const int ko_ = cstg + icq_ * 64;                                      \
    _Pragma("unroll") for (int ms = 0; ms < 7; ++ms) {                     \
      const int s_ = sb[ms] + D_;                                          \
      dst[ms] = *(const v4i*)(As + (s_ << 8) + (ko_ ^ ((s_ & 7) << 4)));   \
    }                                                                      \
  }

#define MFMAC(af, bf)                                                      \
  __builtin_amdgcn_s_setprio(1);                                           \
  _Pragma("unroll") for (int ms = 0; ms < 7; ++ms)                         \
  _Pragma("unroll") for (int ns = 0; ns < 2; ++ns)                         \
      acc[ms][ns] = __builtin_amdgcn_mfma_i32_16x16x64_i8(                 \
          af[ms], bf[ns], acc[ms][ns], 0, 0, 0);                           \
  __builtin_amdgcn_s_setprio(0);

  v4i af[7], bfA[2], bfB[2];
  LOADB(bfA, 0)

#pragma unroll 1
  for (int i = 0; i < 18; ++i) {
    const int s0 = 2 * i, s1 = 2 * i + 1;
    const int s2 = (s1 + 1 > 35) ? 35 : s1 + 1;
    LOADB(bfB, s1)            // prefetch next step's B under this MFMA cluster
    LOADA(af, s0)
    MFMAC(af, bfA)
    LOADB(bfA, s2)
    LOADA(af, s1)
    MFMAC(af, bfB)
  }

#undef MFMAC
#undef LOADA
#undef LOADB

  const int rA = rp * 2;
  if (MODE == 0) {
    // BN1 + sign -> hs (standard NHWC i8)
#pragma unroll
    for (int ns = 0; ns < 2; ++ns) {
      const int oc = wbase + ns * 16 + lid;
      const float mu = mean[oc], rs = rsqrtf(var[oc] + BN_EPS), be = beta[oc];
#pragma unroll
      for (int ms = 0; ms < 7; ++ms)
#pragma unroll
        for (int q = 0; q < 4; ++q) {
          const int m = ms * 16 + grp * 4 + q;
          const int lr = m & 1, col = m >> 1;
          const float bnv = ((float)acc[ms][ns][q] - mu) * rs + be;
          hs[(((size_t)(b * 56 + rA + lr)) * 56 + col) * 256 + oc] =
              bnv >= 0.f ? (int8_t)1 : (int8_t)-1;
        }
    }
  } else {
    // maxpool (lane-local q-quad) + BN2 -> f32
#pragma unroll
    for (int ns = 0; ns < 2; ++ns) {
      const int oc = wbase + ns * 16 + lid;
      const float mu = mean[oc], rs = rsqrtf(var[oc] + BN_EPS), be = beta[oc];
#pragma unroll
      for (int ms = 0; ms < 7; ++ms) {
        const int mx = imax(imax(acc[ms][ns][0], acc[ms][ns][1]),
                            imax(acc[ms][ns][2], acc[ms][ns][3]));
        const int j = ms * 4 + grp;   // pooled col 0..27
        outp[(((size_t)(b * 28 + rp)) * 28 + j) * 256 + oc] =
            ((float)mx - mu) * rs + be;
      }
    }
  }
}

// ---------------------------------------------------------------------------
// 8 waves, each = N=32 slice x all of M=112 (R16 shape). MODE 0 fuses
// sign(x) (R22 staging: 64B/thread f32 read + in-register pack). 1D grid of
// 896 blocks with BIJECTIVE XCD SWIZZLE (R24): XCD k owns images 4k..4k+3
// completely -> halo re-reads and conv1->conv2 hs traffic stay in the
// XCD's 4MB L2.
template <int MODE>
__global__ __launch_bounds__(512, 4) void k_conv(
    const void* __restrict__ srcv, const int8_t* __restrict__ wT2,
    const float* __restrict__ beta, const float* __restrict__ mean,
    const float* __restrict__ var,
    int8_t* __restrict__ hs, float* __restrict__ outp)
{
  const int t = threadIdx.x;
  const int v = blockIdx.x;                 // 0..895
  const int swz = (v & 7) * 112 + (v >> 3); // XCD k -> contiguous 112 blocks
  const int b = swz / 28;                   // image 0..31
  const int rp = swz - b * 28;              // row pair 0..27
  const int rr0 = rp * 2;

  __shared__ __align__(16) int8_t As[NSLOT * 256];   // 59392 B

  // Stage A once (verified R22 pattern; MODE 0 packs f32 -> i8 signs).
  for (int i = t; i < NSLOT * 16; i += 512) {
    const int s = i >> 4, c = i & 15;
    const int lr = s / 58, colst = s - lr * 58;
    const int sr = rr0 + lr - 1, sc = colst - 1;
    uint4 vv;
    vv.x = vv.y = vv.z = vv.w = 0u;
    if ((unsigned)sr < 56u && (unsigned)sc < 56u) {
      if (MODE == 0) {
        const float* p = (const float*)srcv +
                         ((((size_t)(b * 56 + sr)) * 56 + sc) * 256 + c * 16);
        const float4* p4 = (const float4*)p;
        vv.x = pack4(p4[0]); vv.y = pack4(p4[1]);
        vv.z = pack4(p4[2]); vv.w = pack4(p4[3]);
      } else {
        vv = *(const uint4*)((const int8_t*)srcv +
                             (((size_t)(b * 56 + sr)) * 56 + sc) * 256 + c * 16);
      }
    }
    *(uint4*)(As + (s << 8) + ((c << 4) ^ ((s & 7) << 4))) = vv;
  }
  __syncthreads();

  const int lane = t & 63;
  const int wn = t >> 6;              // 0..7
  conv_body<MODE>(As, wT2, wn, lane, beta, mean, var, hs, outp, b, rp);
}

// ---------------------------------------------------------------------------
extern "C" void kernel_launch(void* const* d_in, const int* in_sizes, int n_in,
                              void* d_out, int out_size, void* d_ws, size_t ws_size,
                              hipStream_t stream) {
  const float* x     = (const float*)d_in[0];
  const float* w1    = (const float*)d_in[1];
  const float* beta1 = (const float*)d_in[2];
  const float* mean1 = (const float*)d_in[3];
  const float* var1  = (const float*)d_in[4];
  const float* w2    = (const float*)d_in[5];
  const float* beta2 = (const float*)d_in[6];
  const float* mean2 = (const float*)d_in[7];
  const float* var2  = (const float*)d_in[8];
  float* out = (float*)d_out;

  const size_t NPIX = (size_t)Bn * H * Wd * C;  // 25690112
  int8_t* hs  = (int8_t*)d_ws;
  int8_t* w1t = hs + NPIX;
  int8_t* w2t = w1t + 589824;

  k_sign_wT2<<<dim3(1152), 256, 0, stream>>>(w1, w2, (uint32_t*)w1t,
                                             (uint32_t*)w2t);
  k_conv<0><<<dim3(896), 512, 0, stream>>>(x, w1t, beta1, mean1, var1, hs, nullptr);
  k_conv<1><<<dim3(896), 512, 0, stream>>>(hs, w2t, beta2, mean2, var2, nullptr, out);
}